// Round 3
// baseline (295.987 us; speedup 1.0000x reference)
//
#include <hip/hip_runtime.h>
#include <math.h>

typedef float  f32x4  __attribute__((ext_vector_type(4)));
typedef __bf16 bf16x8 __attribute__((ext_vector_type(8)));
typedef __bf16 bf16x4 __attribute__((ext_vector_type(4)));

__device__ __forceinline__ void gload16(const void* g, void* l) {
  // async global->LDS, 16B per lane; LDS dest = wave-uniform base + lane*16
  __builtin_amdgcn_global_load_lds((__attribute__((address_space(1))) const void*)g,
                                   (__attribute__((address_space(3))) void*)l, 16, 0, 0);
}

__device__ __forceinline__ f32x4 mfma16(bf16x8 a, bf16x8 b, f32x4 c) {
  return __builtin_amdgcn_mfma_f32_16x16x32_bf16(a, b, c, 0, 0, 0);
}

// ---------------------------------------------------------------- weights->bf16 (x4 vectorized)
__global__ __launch_bounds__(256) void cvt_weights(
    const float* __restrict__ Wq, const float* __restrict__ Wk, const float* __restrict__ Wv,
    const float* __restrict__ Wo, const float* __restrict__ W1, const float* __restrict__ W2,
    __bf16* __restrict__ wqkv, __bf16* __restrict__ wo, __bf16* __restrict__ w1, __bf16* __restrict__ w2)
{
  const int idx = (blockIdx.x * 256 + threadIdx.x) * 4;
  const float* src; __bf16* dst; int off;
  if      (idx < 147456) { src = Wq; dst = wqkv;          off = idx; }
  else if (idx < 294912) { src = Wk; dst = wqkv + 147456; off = idx - 147456; }
  else if (idx < 442368) { src = Wv; dst = wqkv + 294912; off = idx - 294912; }
  else if (idx < 589824) { src = Wo; dst = wo;            off = idx - 442368; }
  else if (idx < 884736) { src = W1; dst = w1;            off = idx - 589824; }
  else                   { src = W2; dst = w2;            off = idx - 884736; }
  f32x4 v = *(const f32x4*)(src + off);
  bf16x4 o = {(__bf16)v.x, (__bf16)v.y, (__bf16)v.z, (__bf16)v.w};
  *(bf16x4*)(dst + off) = o;
}

// ---------------------------------------------------------------- layernorm (1 wave = 1 row of 384)
template<int MODE> // 0: bf16 out only; 1: bf16 + f32 out
__global__ __launch_bounds__(256) void ln_kernel(
    const float* __restrict__ in, const float* __restrict__ w, const float* __restrict__ b,
    __bf16* __restrict__ outb, float* __restrict__ outf)
{
  const int row  = blockIdx.x * 4 + (threadIdx.x >> 6);
  const int lane = threadIdx.x & 63;
  const float* x = in + (size_t)row * 384;
  float v[6]; float s = 0.f;
#pragma unroll
  for (int j = 0; j < 6; ++j) { v[j] = x[lane + 64*j]; s += v[j]; }
#pragma unroll
  for (int off = 32; off > 0; off >>= 1) s += __shfl_xor(s, off);
  const float mu = s * (1.f/384.f);
  float s2 = 0.f;
#pragma unroll
  for (int j = 0; j < 6; ++j) { float d = v[j] - mu; s2 += d*d; }
#pragma unroll
  for (int off = 32; off > 0; off >>= 1) s2 += __shfl_xor(s2, off);
  const float inv = rsqrtf(s2 * (1.f/384.f) + 1e-5f);
#pragma unroll
  for (int j = 0; j < 6; ++j) {
    const int cidx = lane + 64*j;
    const float y = (v[j]-mu)*inv*w[cidx] + b[cidx];
    outb[(size_t)row*384 + cidx] = (__bf16)y;
    if constexpr (MODE == 1) outf[(size_t)row*384 + cidx] = y;
  }
}

// ---------------------------------------------------------------- GEMM C = A * B^T (+epilogue)
// A [M,K] bf16 row-major, Bw [N,K] bf16 row-major. 64 x NT tile, BK=32, 4 waves (2x2),
// double-buffered LDS, ONE barrier per K-iter: stage(k+1) -> compute(k) -> sync.
// EPI: 0=scatter q(pre-scaled)/k/v^T  1=+bias+resid->f32  2=+bias,gelu->bf16  3=+bias+=outf
template<int EPI, int NT>
__global__ __launch_bounds__(256, 4) void gemm_bt(
    const __bf16* __restrict__ A, const __bf16* __restrict__ Bw,
    int M, int N, int K,
    const float* __restrict__ bias, const float* __restrict__ resid,
    float* __restrict__ outf, __bf16* __restrict__ outb,
    __bf16* __restrict__ q_out, __bf16* __restrict__ k_out, __bf16* __restrict__ vt_out)
{
  constexpr int CT = NT / 32;  // col-tiles per wave (2 or 4)
  __shared__ __attribute__((aligned(16))) __bf16 As[2][2048];
  __shared__ __attribute__((aligned(16))) __bf16 Bs[2][NT * 32];
  const int tid  = threadIdx.x;
  const int lane = tid & 63;
  const int w    = tid >> 6;
  const int wm   = w >> 1, wn = w & 1;
  const int m0   = blockIdx.y * 64, n0 = blockIdx.x * NT;

  f32x4 acc[2][CT] = {};

  const int srow = lane & 15, skq = lane >> 4;
  const __bf16* gA  = A  + (size_t)(m0 + w*16 + srow) * K + (skq << 3);
  const __bf16* gB0 = Bw + (size_t)(n0 + w*16 + srow) * K + (skq << 3);
  const __bf16* gB1 = Bw + (size_t)(n0 + (4 + w)*16 + srow) * K + (skq << 3);
  const int lbase = (tid & ~63) * 8;

  auto stage = [&](int kk, int b) {
    gload16(gA  + kk*32, &As[b][lbase]);
    gload16(gB0 + kk*32, &Bs[b][lbase]);
    if constexpr (NT == 128) gload16(gB1 + kk*32, &Bs[b][lbase + 2048]);
  };
  auto compute = [&](int b) {
    bf16x8 af[2], bfr[CT];
#pragma unroll
    for (int rt = 0; rt < 2; ++rt)
      af[rt] = *(const bf16x8*)&As[b][(((wm*2 + rt) << 6) + lane) * 8];
#pragma unroll
    for (int ct = 0; ct < CT; ++ct)
      bfr[ct] = *(const bf16x8*)&Bs[b][(((wn*CT + ct) << 6) + lane) * 8];
#pragma unroll
    for (int rt = 0; rt < 2; ++rt)
#pragma unroll
      for (int ct = 0; ct < CT; ++ct)
        acc[rt][ct] = mfma16(af[rt], bfr[ct], acc[rt][ct]);
  };

  const int NIT = K >> 5;
  stage(0, 0);
  __syncthreads();
  for (int k = 0; k < NIT; ++k) {
    const int b = k & 1;
    if (k + 1 < NIT) stage(k + 1, b ^ 1);
    compute(b);
    __syncthreads();
  }

  const int quad = lane >> 4, cc = lane & 15;
#pragma unroll
  for (int rt = 0; rt < 2; ++rt) {
#pragma unroll
    for (int ct = 0; ct < CT; ++ct) {
      const int gr0 = m0 + (wm*2 + rt)*16 + quad*4;
      const int gc  = n0 + (wn*CT + ct)*16 + cc;
      f32x4 a = acc[rt][ct];
      if constexpr (EPI == 0) {
        const int bb = gr0 >> 10, nn = gr0 & 1023;  // gr0 % 4 == 0, no 1024-crossing in 4 rows
        if (gc >= 768) {
          // v: write transposed [B,H,64,N], packed 4 consecutive n
          const int jj = gc - 768, hh = jj >> 6, dh = jj & 63;
          bf16x4 pk = {(__bf16)a[0], (__bf16)a[1], (__bf16)a[2], (__bf16)a[3]};
          *(bf16x4*)&vt_out[((size_t)((bb*6 + hh)*64 + dh) << 10) + nn] = pk;
        } else {
          const bool isq = (gc < 384);
          const int jj = isq ? gc : (gc - 384);
          __bf16* dst = isq ? q_out : k_out;
          const float sc = isq ? 0.18033688011112042f : 1.0f; // (1/8)*log2(e) folded into q
          const int hh = jj >> 6, dh = jj & 63;
#pragma unroll
          for (int i = 0; i < 4; ++i)
            dst[((size_t)(((bb*6 + hh) << 10) | (nn + i)) << 6) + dh] = (__bf16)(a[i] * sc);
        }
      } else {
#pragma unroll
        for (int i = 0; i < 4; ++i) {
          const int gr = gr0 + i;
          float val = a[i];
          if constexpr (EPI == 1) {
            const size_t idx = (size_t)gr * N + gc;
            outf[idx] = val + bias[gc] + resid[idx];
          } else if constexpr (EPI == 2) {
            const float x = val + bias[gc];
            outb[(size_t)gr * N + gc] = (__bf16)(0.5f * x * (1.f + erff(x * 0.70710678118654752f)));
          } else {
            const size_t idx = (size_t)gr * N + gc;
            outf[idx] = outf[idx] + val + bias[gc];
          }
        }
      }
    }
  }
}

// ---------------------------------------------------------------- flash attention v3
// S^T = K*Q^T orientation, no max subtraction (scores ~|1|, scale*log2e folded into q),
// double-buffered K/V staging, one barrier per chunk. grid (96 bh, 8 qtiles):
// 96 % 8 == 0 -> all q-tiles of a bh on one XCD, K/V L2-resident.
__global__ __launch_bounds__(256, 3) void attn_kernel(
    const __bf16* __restrict__ qp, const __bf16* __restrict__ kp,
    const __bf16* __restrict__ vtp, __bf16* __restrict__ omat)
{
  __shared__ __attribute__((aligned(16))) __bf16 Ks[2][4096];     // 64 keys x 64 d, frag-ordered
  __shared__ __attribute__((aligned(16))) __bf16 Vs[2][4096];     // 64 d x 64 keys (from v^T)
  __shared__ __attribute__((aligned(16))) __bf16 Ps[4][2][1088];  // per-wave per-qtile 16 x 68
  const int tid = threadIdx.x, lane = tid & 63, w = tid >> 6;
  const int bh = blockIdx.x;
  const int q0 = blockIdx.y * 128 + w * 32;
  const int quad = lane >> 4, lo = lane & 15;

  // Q as B-operand fragments (lane&15 = q, quad*8+j = d), held in registers
  bf16x8 qa[2][2];
#pragma unroll
  for (int t = 0; t < 2; ++t) {
    const __bf16* qb = qp + ((size_t)bh * 1024 + q0 + t*16 + lo) * 64 + (quad << 3);
    qa[t][0] = *(const bf16x8*)qb;
    qa[t][1] = *(const bf16x8*)(qb + 32);
  }

  f32x4 oacc[2][4] = {};
  float l_r[2] = {0.f, 0.f};

  auto stage = [&](int c, int bb) {
#pragma unroll
    for (int s = 0; s < 2; ++s) {
      const int ck = s * 256 + tid;
      const int l = ck & 63, g = ck >> 6;       // g in [0,8)
      const int ct = g >> 1, ks = g & 1;
      const __bf16* gk = kp + ((size_t)bh*1024 + c*64 + ct*16 + (l & 15)) * 64
                            + ks*32 + ((l >> 4) << 3);
      gload16(gk, &Ks[bb][(ck & ~63) * 8]);
      const __bf16* gv = vtp + (((size_t)(bh*64 + ct*16 + (l & 15))) << 10)
                             + c*64 + ks*32 + ((l >> 4) << 3);
      gload16(gv, &Vs[bb][(ck & ~63) * 8]);
    }
  };

  stage(0, 0);
  __syncthreads();

  for (int c = 0; c < 16; ++c) {
    const int bb = c & 1;
    if (c + 1 < 16) stage(c + 1, bb ^ 1);

    // S^T tiles: D[m=key][n=q]; lane holds q=lo, keys quad*4+i
    f32x4 st[2][4];
#pragma unroll
    for (int ct = 0; ct < 4; ++ct) {
      bf16x8 kb0 = *(const bf16x8*)&Ks[bb][((ct*2 + 0)*64 + lane) * 8];
      bf16x8 kb1 = *(const bf16x8*)&Ks[bb][((ct*2 + 1)*64 + lane) * 8];
#pragma unroll
      for (int t = 0; t < 2; ++t) {
        f32x4 s0 = {};
        s0 = mfma16(kb0, qa[t][0], s0);
        s0 = mfma16(kb1, qa[t][1], s0);
        st[t][ct] = s0;
      }
    }
    // p = exp2(s); in-lane row-sum accumulation; packed b64 store
#pragma unroll
    for (int t = 0; t < 2; ++t)
#pragma unroll
      for (int ct = 0; ct < 4; ++ct) {
        const float p0 = __builtin_amdgcn_exp2f(st[t][ct][0]);
        const float p1 = __builtin_amdgcn_exp2f(st[t][ct][1]);
        const float p2 = __builtin_amdgcn_exp2f(st[t][ct][2]);
        const float p3 = __builtin_amdgcn_exp2f(st[t][ct][3]);
        l_r[t] += (p0 + p1) + (p2 + p3);
        bf16x4 pk = {(__bf16)p0, (__bf16)p1, (__bf16)p2, (__bf16)p3};
        *(bf16x4*)&Ps[w][t][lo*68 + ct*16 + quad*4] = pk;
      }
    // P as A-operand (lane&15 = q, quad*8+j = key)
    bf16x8 pa[2][2];
#pragma unroll
    for (int t = 0; t < 2; ++t)
#pragma unroll
      for (int ks = 0; ks < 2; ++ks)
        pa[t][ks] = *(const bf16x8*)&Ps[w][t][lo*68 + ks*32 + (quad << 3)];
    // O += P V
#pragma unroll
    for (int dt = 0; dt < 4; ++dt)
#pragma unroll
      for (int ks = 0; ks < 2; ++ks) {
        bf16x8 vb = *(const bf16x8*)&Vs[bb][((dt*2 + ks)*64 + lane) * 8];
#pragma unroll
        for (int t = 0; t < 2; ++t)
          oacc[t][dt] = mfma16(pa[t][ks], vb, oacc[t][dt]);
      }
    __syncthreads();
  }

  const int b = bh / 6, h = bh - (bh / 6) * 6;
#pragma unroll
  for (int t = 0; t < 2; ++t) {
    float ls = l_r[t];
    ls += __shfl_xor(ls, 16);
    ls += __shfl_xor(ls, 32);   // lane now holds sum for q = lane&15
#pragma unroll
    for (int i = 0; i < 4; ++i) {
      const float linv = 1.f / __shfl(ls, quad*4 + i);
      const int n = q0 + t*16 + quad*4 + i;
#pragma unroll
      for (int dt = 0; dt < 4; ++dt)
        omat[((size_t)((b << 10) | n)) * 384 + (h << 6) + dt*16 + lo] =
            (__bf16)(oacc[t][dt][i] * linv);
    }
  }
}

// ---------------------------------------------------------------- launch
extern "C" void kernel_launch(void* const* d_in, const int* in_sizes, int n_in,
                              void* d_out, int out_size, void* d_ws, size_t ws_size,
                              hipStream_t stream)
{
  const float* X    = (const float*)d_in[0];
  const float* Wq   = (const float*)d_in[1];
  const float* Wk   = (const float*)d_in[2];
  const float* Wv   = (const float*)d_in[3];
  const float* Wo   = (const float*)d_in[4];
  const float* bo   = (const float*)d_in[5];
  const float* ln1w = (const float*)d_in[6];
  const float* ln1b = (const float*)d_in[7];
  const float* ln2w = (const float*)d_in[8];
  const float* ln2b = (const float*)d_in[9];
  const float* W1   = (const float*)d_in[10];
  const float* b1   = (const float*)d_in[11];
  const float* W2   = (const float*)d_in[12];
  const float* b2   = (const float*)d_in[13];

  char* ws = (char*)d_ws;
  __bf16* t_bf  = (__bf16*)(ws + 0);           // [16384,384] bf16; reused as X2 bf16
  __bf16* q_bf  = (__bf16*)(ws + 12582912);    // [B,H,N,64] (pre-scaled by log2e/8)
  __bf16* k_bf  = (__bf16*)(ws + 25165824);    // [B,H,N,64]
  __bf16* omat  = (__bf16*)(ws + 37748736);    // [B,N,384] attention output
  __bf16* vt_bf = (__bf16*)(ws + 50331648);    // [B,H,64,N]
  float*  s1    = (float*) (ws + 62914560);    // [16384,384] f32; reused as h bf16
  __bf16* h_bf  = (__bf16*)(ws + 62914560);    // [16384,768] bf16
  __bf16* wqkv  = (__bf16*)(ws + 88080384);    // [1152,384]
  __bf16* wo_b  = (__bf16*)(ws + 88965120);    // [384,384]
  __bf16* w1_b  = (__bf16*)(ws + 89260032);    // [768,384]
  __bf16* w2_b  = (__bf16*)(ws + 89849856);    // [384,768]
  __bf16* x2_bf = t_bf;
  float*  out   = (float*)d_out;

  cvt_weights<<<1152, 256, 0, stream>>>(Wq, Wk, Wv, Wo, W1, W2, wqkv, wo_b, w1_b, w2_b);
  ln_kernel<0><<<4096, 256, 0, stream>>>(X, ln1w, ln1b, t_bf, nullptr);
  gemm_bt<0,128><<<dim3(9,256), 256, 0, stream>>>(t_bf, wqkv, 16384, 1152, 384,
      nullptr, nullptr, nullptr, nullptr, q_bf, k_bf, vt_bf);
  attn_kernel<<<dim3(96,8), 256, 0, stream>>>(q_bf, k_bf, vt_bf, omat);
  gemm_bt<1,64><<<dim3(6,256), 256, 0, stream>>>(omat, wo_b, 16384, 384, 384,
      bo, X, s1, nullptr, nullptr, nullptr, nullptr);
  ln_kernel<1><<<4096, 256, 0, stream>>>(s1, ln2w, ln2b, x2_bf, out);
  gemm_bt<2,128><<<dim3(6,256), 256, 0, stream>>>(x2_bf, w1_b, 16384, 768, 384,
      b1, nullptr, nullptr, h_bf, nullptr, nullptr, nullptr);
  gemm_bt<3,64><<<dim3(6,256), 256, 0, stream>>>(h_bf, w2_b, 16384, 384, 768,
      b2, nullptr, out, nullptr, nullptr, nullptr, nullptr);
}

// Round 4
// 279.155 us; speedup vs baseline: 1.0603x; 1.0603x over previous
//
#include <hip/hip_runtime.h>
#include <math.h>

typedef float  f32x4  __attribute__((ext_vector_type(4)));
typedef __bf16 bf16x8 __attribute__((ext_vector_type(8)));
typedef __bf16 bf16x4 __attribute__((ext_vector_type(4)));

__device__ __forceinline__ void gload16(const void* g, void* l) {
  // async global->LDS, 16B per lane; LDS dest = wave-uniform base + lane*16
  __builtin_amdgcn_global_load_lds((__attribute__((address_space(1))) const void*)g,
                                   (__attribute__((address_space(3))) void*)l, 16, 0, 0);
}

__device__ __forceinline__ f32x4 mfma16(bf16x8 a, bf16x8 b, f32x4 c) {
  return __builtin_amdgcn_mfma_f32_16x16x32_bf16(a, b, c, 0, 0, 0);
}

// ---------------------------------------------------------------- weights->bf16 (x4 vectorized)
__global__ __launch_bounds__(256) void cvt_weights(
    const float* __restrict__ Wq, const float* __restrict__ Wk, const float* __restrict__ Wv,
    const float* __restrict__ Wo, const float* __restrict__ W1, const float* __restrict__ W2,
    __bf16* __restrict__ wqkv, __bf16* __restrict__ wo, __bf16* __restrict__ w1, __bf16* __restrict__ w2)
{
  const int idx = (blockIdx.x * 256 + threadIdx.x) * 4;
  const float* src; __bf16* dst; int off;
  if      (idx < 147456) { src = Wq; dst = wqkv;          off = idx; }
  else if (idx < 294912) { src = Wk; dst = wqkv + 147456; off = idx - 147456; }
  else if (idx < 442368) { src = Wv; dst = wqkv + 294912; off = idx - 294912; }
  else if (idx < 589824) { src = Wo; dst = wo;            off = idx - 442368; }
  else if (idx < 884736) { src = W1; dst = w1;            off = idx - 589824; }
  else                   { src = W2; dst = w2;            off = idx - 884736; }
  f32x4 v = *(const f32x4*)(src + off);
  bf16x4 o = {(__bf16)v.x, (__bf16)v.y, (__bf16)v.z, (__bf16)v.w};
  *(bf16x4*)(dst + off) = o;
}

// ---------------------------------------------------------------- layernorm (1 wave = 1 row of 384)
template<int MODE> // 0: bf16 out only; 1: bf16 + f32 out
__global__ __launch_bounds__(256) void ln_kernel(
    const float* __restrict__ in, const float* __restrict__ w, const float* __restrict__ b,
    __bf16* __restrict__ outb, float* __restrict__ outf)
{
  const int row  = blockIdx.x * 4 + (threadIdx.x >> 6);
  const int lane = threadIdx.x & 63;
  const float* x = in + (size_t)row * 384;
  float v[6]; float s = 0.f;
#pragma unroll
  for (int j = 0; j < 6; ++j) { v[j] = x[lane + 64*j]; s += v[j]; }
#pragma unroll
  for (int off = 32; off > 0; off >>= 1) s += __shfl_xor(s, off);
  const float mu = s * (1.f/384.f);
  float s2 = 0.f;
#pragma unroll
  for (int j = 0; j < 6; ++j) { float d = v[j] - mu; s2 += d*d; }
#pragma unroll
  for (int off = 32; off > 0; off >>= 1) s2 += __shfl_xor(s2, off);
  const float inv = rsqrtf(s2 * (1.f/384.f) + 1e-5f);
#pragma unroll
  for (int j = 0; j < 6; ++j) {
    const int cidx = lane + 64*j;
    const float y = (v[j]-mu)*inv*w[cidx] + b[cidx];
    outb[(size_t)row*384 + cidx] = (__bf16)y;
    if constexpr (MODE == 1) outf[(size_t)row*384 + cidx] = y;
  }
}

// ---------------------------------------------------------------- GEMM C = A * B^T (+epilogue)
// A [M,K] bf16 row-major, Bw [N,K] bf16 row-major. 128 x NT tile, BK=32, 4 waves (2x2),
// 64 x (NT/2) per wave = 16 (or 8) MFMA per K-iter per wave; double-buffered LDS,
// ONE barrier per K-iter: stage(k+1) -> compute(k) -> sync.
// EPI: 0=scatter q(pre-scaled)/k/v^T  1=+bias+resid->f32  2=+bias,gelu->bf16  3=+bias+=outf
template<int EPI, int NT>
__global__ __launch_bounds__(256, NT == 128 ? 3 : 4) void gemm_bt(
    const __bf16* __restrict__ A, const __bf16* __restrict__ Bw,
    int M, int N, int K,
    const float* __restrict__ bias, const float* __restrict__ resid,
    float* __restrict__ outf, __bf16* __restrict__ outb,
    __bf16* __restrict__ q_out, __bf16* __restrict__ k_out, __bf16* __restrict__ vt_out)
{
  constexpr int CT     = NT / 32;        // col-subtiles per wave
  constexpr int BSUB   = NT / 16;        // B subtiles per buffer
  constexpr int ROUNDS = (8 + BSUB) / 4; // staging rounds (4 waves each stage 1 subtile/round)
  __shared__ __attribute__((aligned(16))) __bf16 As[2][4096];
  __shared__ __attribute__((aligned(16))) __bf16 Bs[2][NT * 32];
  const int tid  = threadIdx.x;
  const int lane = tid & 63;
  const int w    = tid >> 6;
  const int wm   = w >> 1, wn = w & 1;
  const int m0   = blockIdx.y * 128, n0 = blockIdx.x * NT;

  f32x4 acc[4][CT] = {};

  const int srow = lane & 15, skq = lane >> 4;
  // per-round staging sources/destinations (subtile id = r*4 + w)
  const __bf16* gptr[ROUNDS];
  __bf16*       lptr[ROUNDS];   // dest in buffer 0
  int           lstr[ROUNDS];   // element stride buffer0 -> buffer1
#pragma unroll
  for (int r = 0; r < ROUNDS; ++r) {
    const int id = r * 4 + w;
    if (id < 8) {
      gptr[r] = A + (size_t)(m0 + id*16 + srow) * K + (skq << 3);
      lptr[r] = &As[0][id * 512];
      lstr[r] = 4096;
    } else {
      const int j = id - 8;
      gptr[r] = Bw + (size_t)(n0 + j*16 + srow) * K + (skq << 3);
      lptr[r] = &Bs[0][j * 512];
      lstr[r] = NT * 32;
    }
  }

  auto stage = [&](int kk, int b) {
#pragma unroll
    for (int r = 0; r < ROUNDS; ++r)
      gload16(gptr[r] + kk * 32, lptr[r] + b * lstr[r]);
  };
  auto compute = [&](int b) {
    bf16x8 af[4], bfr[CT];
#pragma unroll
    for (int i = 0; i < 4; ++i)
      af[i] = *(const bf16x8*)&As[b][(wm*4 + i) * 512 + lane * 8];
#pragma unroll
    for (int j = 0; j < CT; ++j)
      bfr[j] = *(const bf16x8*)&Bs[b][(wn*CT + j) * 512 + lane * 8];
#pragma unroll
    for (int i = 0; i < 4; ++i)
#pragma unroll
      for (int j = 0; j < CT; ++j)
        acc[i][j] = mfma16(af[i], bfr[j], acc[i][j]);
  };

  const int NIT = K >> 5;
  stage(0, 0);
  __syncthreads();
  for (int k = 0; k < NIT; ++k) {
    const int b = k & 1;
    if (k + 1 < NIT) stage(k + 1, b ^ 1);
    compute(b);
    __syncthreads();
  }

  const int quad = lane >> 4, cc = lane & 15;
#pragma unroll
  for (int rt = 0; rt < 4; ++rt) {
#pragma unroll
    for (int ct = 0; ct < CT; ++ct) {
      const int gr0 = m0 + (wm*4 + rt)*16 + quad*4;
      const int gc  = n0 + (wn*CT + ct)*16 + cc;
      f32x4 a = acc[rt][ct];
      if constexpr (EPI == 0) {
        const int bb = gr0 >> 10, nn = gr0 & 1023;  // gr0 % 4 == 0, no 1024-crossing in 4 rows
        if (gc >= 768) {
          // v: write transposed [B,H,64,N], packed 4 consecutive n
          const int jj = gc - 768, hh = jj >> 6, dh = jj & 63;
          bf16x4 pk = {(__bf16)a[0], (__bf16)a[1], (__bf16)a[2], (__bf16)a[3]};
          *(bf16x4*)&vt_out[((size_t)((bb*6 + hh)*64 + dh) << 10) + nn] = pk;
        } else {
          const bool isq = (gc < 384);
          const int jj = isq ? gc : (gc - 384);
          __bf16* dst = isq ? q_out : k_out;
          const float sc = isq ? 0.18033688011112042f : 1.0f; // (1/8)*log2(e) folded into q
          const int hh = jj >> 6, dh = jj & 63;
#pragma unroll
          for (int i = 0; i < 4; ++i)
            dst[((size_t)(((bb*6 + hh) << 10) | (nn + i)) << 6) + dh] = (__bf16)(a[i] * sc);
        }
      } else {
#pragma unroll
        for (int i = 0; i < 4; ++i) {
          const int gr = gr0 + i;
          float val = a[i];
          if constexpr (EPI == 1) {
            const size_t idx = (size_t)gr * N + gc;
            outf[idx] = val + bias[gc] + resid[idx];
          } else if constexpr (EPI == 2) {
            const float x = val + bias[gc];
            outb[(size_t)gr * N + gc] = (__bf16)(0.5f * x * (1.f + erff(x * 0.70710678118654752f)));
          } else {
            const size_t idx = (size_t)gr * N + gc;
            outf[idx] = outf[idx] + val + bias[gc];
          }
        }
      }
    }
  }
}

// ---------------------------------------------------------------- flash attention v3
// S^T = K*Q^T orientation, no max subtraction (scores ~|1|, scale*log2e folded into q),
// double-buffered K/V staging, one barrier per chunk. grid (96 bh, 8 qtiles):
// 96 % 8 == 0 -> all q-tiles of a bh on one XCD, K/V L2-resident.
__global__ __launch_bounds__(256, 3) void attn_kernel(
    const __bf16* __restrict__ qp, const __bf16* __restrict__ kp,
    const __bf16* __restrict__ vtp, __bf16* __restrict__ omat)
{
  __shared__ __attribute__((aligned(16))) __bf16 Ks[2][4096];     // 64 keys x 64 d, frag-ordered
  __shared__ __attribute__((aligned(16))) __bf16 Vs[2][4096];     // 64 d x 64 keys (from v^T)
  __shared__ __attribute__((aligned(16))) __bf16 Ps[4][2][1088];  // per-wave per-qtile 16 x 68
  const int tid = threadIdx.x, lane = tid & 63, w = tid >> 6;
  const int bh = blockIdx.x;
  const int q0 = blockIdx.y * 128 + w * 32;
  const int quad = lane >> 4, lo = lane & 15;

  // Q as B-operand fragments (lane&15 = q, quad*8+j = d), held in registers
  bf16x8 qa[2][2];
#pragma unroll
  for (int t = 0; t < 2; ++t) {
    const __bf16* qb = qp + ((size_t)bh * 1024 + q0 + t*16 + lo) * 64 + (quad << 3);
    qa[t][0] = *(const bf16x8*)qb;
    qa[t][1] = *(const bf16x8*)(qb + 32);
  }

  f32x4 oacc[2][4] = {};
  float l_r[2] = {0.f, 0.f};

  auto stage = [&](int c, int bb) {
#pragma unroll
    for (int s = 0; s < 2; ++s) {
      const int ck = s * 256 + tid;
      const int l = ck & 63, g = ck >> 6;       // g in [0,8)
      const int ct = g >> 1, ks = g & 1;
      const __bf16* gk = kp + ((size_t)bh*1024 + c*64 + ct*16 + (l & 15)) * 64
                            + ks*32 + ((l >> 4) << 3);
      gload16(gk, &Ks[bb][(ck & ~63) * 8]);
      const __bf16* gv = vtp + (((size_t)(bh*64 + ct*16 + (l & 15))) << 10)
                             + c*64 + ks*32 + ((l >> 4) << 3);
      gload16(gv, &Vs[bb][(ck & ~63) * 8]);
    }
  };

  stage(0, 0);
  __syncthreads();

  for (int c = 0; c < 16; ++c) {
    const int bb = c & 1;
    if (c + 1 < 16) stage(c + 1, bb ^ 1);

    // S^T tiles: D[m=key][n=q]; lane holds q=lo, keys quad*4+i
    f32x4 st[2][4];
#pragma unroll
    for (int ct = 0; ct < 4; ++ct) {
      bf16x8 kb0 = *(const bf16x8*)&Ks[bb][((ct*2 + 0)*64 + lane) * 8];
      bf16x8 kb1 = *(const bf16x8*)&Ks[bb][((ct*2 + 1)*64 + lane) * 8];
#pragma unroll
      for (int t = 0; t < 2; ++t) {
        f32x4 s0 = {};
        s0 = mfma16(kb0, qa[t][0], s0);
        s0 = mfma16(kb1, qa[t][1], s0);
        st[t][ct] = s0;
      }
    }
    // p = exp2(s); in-lane row-sum accumulation; packed b64 store
#pragma unroll
    for (int t = 0; t < 2; ++t)
#pragma unroll
      for (int ct = 0; ct < 4; ++ct) {
        const float p0 = __builtin_amdgcn_exp2f(st[t][ct][0]);
        const float p1 = __builtin_amdgcn_exp2f(st[t][ct][1]);
        const float p2 = __builtin_amdgcn_exp2f(st[t][ct][2]);
        const float p3 = __builtin_amdgcn_exp2f(st[t][ct][3]);
        l_r[t] += (p0 + p1) + (p2 + p3);
        bf16x4 pk = {(__bf16)p0, (__bf16)p1, (__bf16)p2, (__bf16)p3};
        *(bf16x4*)&Ps[w][t][lo*68 + ct*16 + quad*4] = pk;
      }
    // P as A-operand (lane&15 = q, quad*8+j = key)
    bf16x8 pa[2][2];
#pragma unroll
    for (int t = 0; t < 2; ++t)
#pragma unroll
      for (int ks = 0; ks < 2; ++ks)
        pa[t][ks] = *(const bf16x8*)&Ps[w][t][lo*68 + ks*32 + (quad << 3)];
    // O += P V
#pragma unroll
    for (int dt = 0; dt < 4; ++dt)
#pragma unroll
      for (int ks = 0; ks < 2; ++ks) {
        bf16x8 vb = *(const bf16x8*)&Vs[bb][((dt*2 + ks)*64 + lane) * 8];
#pragma unroll
        for (int t = 0; t < 2; ++t)
          oacc[t][dt] = mfma16(pa[t][ks], vb, oacc[t][dt]);
      }
    __syncthreads();
  }

  const int b = bh / 6, h = bh - (bh / 6) * 6;
#pragma unroll
  for (int t = 0; t < 2; ++t) {
    float ls = l_r[t];
    ls += __shfl_xor(ls, 16);
    ls += __shfl_xor(ls, 32);   // lane now holds sum for q = lane&15
#pragma unroll
    for (int i = 0; i < 4; ++i) {
      const float linv = 1.f / __shfl(ls, quad*4 + i);
      const int n = q0 + t*16 + quad*4 + i;
#pragma unroll
      for (int dt = 0; dt < 4; ++dt)
        omat[((size_t)((b << 10) | n)) * 384 + (h << 6) + dt*16 + lo] =
            (__bf16)(oacc[t][dt][i] * linv);
    }
  }
}

// ---------------------------------------------------------------- launch
extern "C" void kernel_launch(void* const* d_in, const int* in_sizes, int n_in,
                              void* d_out, int out_size, void* d_ws, size_t ws_size,
                              hipStream_t stream)
{
  const float* X    = (const float*)d_in[0];
  const float* Wq   = (const float*)d_in[1];
  const float* Wk   = (const float*)d_in[2];
  const float* Wv   = (const float*)d_in[3];
  const float* Wo   = (const float*)d_in[4];
  const float* bo   = (const float*)d_in[5];
  const float* ln1w = (const float*)d_in[6];
  const float* ln1b = (const float*)d_in[7];
  const float* ln2w = (const float*)d_in[8];
  const float* ln2b = (const float*)d_in[9];
  const float* W1   = (const float*)d_in[10];
  const float* b1   = (const float*)d_in[11];
  const float* W2   = (const float*)d_in[12];
  const float* b2   = (const float*)d_in[13];

  char* ws = (char*)d_ws;
  __bf16* t_bf  = (__bf16*)(ws + 0);           // [16384,384] bf16; reused as X2 bf16
  __bf16* q_bf  = (__bf16*)(ws + 12582912);    // [B,H,N,64] (pre-scaled by log2e/8)
  __bf16* k_bf  = (__bf16*)(ws + 25165824);    // [B,H,N,64]
  __bf16* omat  = (__bf16*)(ws + 37748736);    // [B,N,384] attention output
  __bf16* vt_bf = (__bf16*)(ws + 50331648);    // [B,H,64,N]
  float*  s1    = (float*) (ws + 62914560);    // [16384,384] f32; reused as h bf16
  __bf16* h_bf  = (__bf16*)(ws + 62914560);    // [16384,768] bf16
  __bf16* wqkv  = (__bf16*)(ws + 88080384);    // [1152,384]
  __bf16* wo_b  = (__bf16*)(ws + 88965120);    // [384,384]
  __bf16* w1_b  = (__bf16*)(ws + 89260032);    // [768,384]
  __bf16* w2_b  = (__bf16*)(ws + 89849856);    // [384,768]
  __bf16* x2_bf = t_bf;
  float*  out   = (float*)d_out;

  cvt_weights<<<1152, 256, 0, stream>>>(Wq, Wk, Wv, Wo, W1, W2, wqkv, wo_b, w1_b, w2_b);
  ln_kernel<0><<<4096, 256, 0, stream>>>(X, ln1w, ln1b, t_bf, nullptr);
  gemm_bt<0,128><<<dim3(9,128), 256, 0, stream>>>(t_bf, wqkv, 16384, 1152, 384,
      nullptr, nullptr, nullptr, nullptr, q_bf, k_bf, vt_bf);
  attn_kernel<<<dim3(96,8), 256, 0, stream>>>(q_bf, k_bf, vt_bf, omat);
  gemm_bt<1,64><<<dim3(6,128), 256, 0, stream>>>(omat, wo_b, 16384, 384, 384,
      bo, X, s1, nullptr, nullptr, nullptr, nullptr);
  ln_kernel<1><<<4096, 256, 0, stream>>>(s1, ln2w, ln2b, x2_bf, out);
  gemm_bt<2,128><<<dim3(6,128), 256, 0, stream>>>(x2_bf, w1_b, 16384, 768, 384,
      b1, nullptr, nullptr, h_bf, nullptr, nullptr, nullptr);
  gemm_bt<3,64><<<dim3(6,128), 256, 0, stream>>>(h_bf, w2_b, 16384, 384, 768,
      b2, nullptr, out, nullptr, nullptr, nullptr, nullptr);
}

// Round 5
// 274.393 us; speedup vs baseline: 1.0787x; 1.0174x over previous
//
#include <hip/hip_runtime.h>
#include <math.h>

typedef float  f32x4  __attribute__((ext_vector_type(4)));
typedef __bf16 bf16x8 __attribute__((ext_vector_type(8)));
typedef __bf16 bf16x4 __attribute__((ext_vector_type(4)));

__device__ __forceinline__ void gload16(const void* g, void* l) {
  // async global->LDS, 16B per lane; LDS dest = wave-uniform base + lane*16
  __builtin_amdgcn_global_load_lds((__attribute__((address_space(1))) const void*)g,
                                   (__attribute__((address_space(3))) void*)l, 16, 0, 0);
}

__device__ __forceinline__ f32x4 mfma16(bf16x8 a, bf16x8 b, f32x4 c) {
  return __builtin_amdgcn_mfma_f32_16x16x32_bf16(a, b, c, 0, 0, 0);
}

// fast exact-GELU: A&S 7.1.26 erf approx, |err_erf| < 1.5e-7 (<< 0.03 absmax slack)
__device__ __forceinline__ float fast_gelu(float x) {
  const float xs = x * 0.70710678118654752f;
  const float ax = fabsf(xs);
  const float t  = __builtin_amdgcn_rcpf(1.f + 0.3275911f * ax);
  const float poly = ((((1.061405429f*t - 1.453152027f)*t + 1.421413741f)*t
                       - 0.284496736f)*t + 0.254829592f)*t;
  const float e = __builtin_amdgcn_exp2f(-1.4426950408889634f * ax * ax);
  float erfv = 1.f - poly * e;
  erfv = (xs < 0.f) ? -erfv : erfv;
  return 0.5f * x * (1.f + erfv);
}

// ---------------------------------------------------------------- weights->bf16 (x4 vectorized)
__global__ __launch_bounds__(256) void cvt_weights(
    const float* __restrict__ Wq, const float* __restrict__ Wk, const float* __restrict__ Wv,
    const float* __restrict__ Wo, const float* __restrict__ W1, const float* __restrict__ W2,
    __bf16* __restrict__ wqkv, __bf16* __restrict__ wo, __bf16* __restrict__ w1, __bf16* __restrict__ w2)
{
  const int idx = (blockIdx.x * 256 + threadIdx.x) * 4;
  const float* src; __bf16* dst; int off;
  if      (idx < 147456) { src = Wq; dst = wqkv;          off = idx; }
  else if (idx < 294912) { src = Wk; dst = wqkv + 147456; off = idx - 147456; }
  else if (idx < 442368) { src = Wv; dst = wqkv + 294912; off = idx - 294912; }
  else if (idx < 589824) { src = Wo; dst = wo;            off = idx - 442368; }
  else if (idx < 884736) { src = W1; dst = w1;            off = idx - 589824; }
  else                   { src = W2; dst = w2;            off = idx - 884736; }
  f32x4 v = *(const f32x4*)(src + off);
  bf16x4 o = {(__bf16)v.x, (__bf16)v.y, (__bf16)v.z, (__bf16)v.w};
  *(bf16x4*)(dst + off) = o;
}

// ---------------------------------------------------------------- layernorm (1 wave = 1 row of 384)
template<int MODE> // 0: bf16 out only; 1: bf16 + f32 out
__global__ __launch_bounds__(256) void ln_kernel(
    const float* __restrict__ in, const float* __restrict__ w, const float* __restrict__ b,
    __bf16* __restrict__ outb, float* __restrict__ outf)
{
  const int row  = blockIdx.x * 4 + (threadIdx.x >> 6);
  const int lane = threadIdx.x & 63;
  const float* x = in + (size_t)row * 384;
  float v[6]; float s = 0.f;
#pragma unroll
  for (int j = 0; j < 6; ++j) { v[j] = x[lane + 64*j]; s += v[j]; }
#pragma unroll
  for (int off = 32; off > 0; off >>= 1) s += __shfl_xor(s, off);
  const float mu = s * (1.f/384.f);
  float s2 = 0.f;
#pragma unroll
  for (int j = 0; j < 6; ++j) { float d = v[j] - mu; s2 += d*d; }
#pragma unroll
  for (int off = 32; off > 0; off >>= 1) s2 += __shfl_xor(s2, off);
  const float inv = rsqrtf(s2 * (1.f/384.f) + 1e-5f);
#pragma unroll
  for (int j = 0; j < 6; ++j) {
    const int cidx = lane + 64*j;
    const float y = (v[j]-mu)*inv*w[cidx] + b[cidx];
    outb[(size_t)row*384 + cidx] = (__bf16)y;
    if constexpr (MODE == 1) outf[(size_t)row*384 + cidx] = y;
  }
}

// ---------------------------------------------------------------- GEMM C = A * B^T (+epilogue)
// A [M,K] bf16 row-major, Bw [N,K] bf16 row-major. 128 x NT tile, BK per barrier interval,
// 4 waves (2x2), double-buffered LDS, ONE barrier per K-iter.
// grid: x = m-tile (fast), y = n-tile  -> blocks sharing an A-tile differ by gridDim.x
// (multiple of 8) in linear id -> same XCD -> A-tile L2-resident (low RT).
// BK=64 doubles bytes-in-flight per block (the R4 counter model: thin-grid GEMMs sit at
// a ~2.3 TB/s staging equilibrium = blocks/CU x inflight/RT; raise inflight, cut RT).
// EPI: 0=scatter q(pre-scaled)/k/v^T  1=+bias+resid->f32  2=+bias,gelu->bf16  3=+bias+=outf
template<int EPI, int NT, int BK>
__global__ __launch_bounds__(256, (NT == 128 && BK == 64) ? 2 : 3) void gemm_bt(
    const __bf16* __restrict__ A, const __bf16* __restrict__ Bw,
    int M, int N, int K,
    const float* __restrict__ bias, const float* __restrict__ resid,
    float* __restrict__ outf, __bf16* __restrict__ outb,
    __bf16* __restrict__ q_out, __bf16* __restrict__ k_out, __bf16* __restrict__ vt_out)
{
  constexpr int CT     = NT / 32;          // col-subtiles per wave
  constexpr int KS     = BK / 32;          // k-substeps per barrier interval
  constexpr int ASUB   = 8 * KS;           // A 16x32 subtiles per buffer
  constexpr int BSUB   = (NT / 16) * KS;   // B subtiles per buffer
  constexpr int ROUNDS = (ASUB + BSUB) / 4;
  __shared__ __attribute__((aligned(16))) __bf16 As[2][4096 * KS];
  __shared__ __attribute__((aligned(16))) __bf16 Bs[2][NT * 32 * KS];
  const int tid  = threadIdx.x;
  const int lane = tid & 63;
  const int w    = tid >> 6;
  const int wm   = w >> 1, wn = w & 1;
  const int m0   = blockIdx.x * 128, n0 = blockIdx.y * NT;

  f32x4 acc[4][CT] = {};

  const int srow = lane & 15, skq = lane >> 4;
  // per-round staging sources/destinations (subtile id = r*4 + w)
  const __bf16* gptr[ROUNDS];
  __bf16*       lptr[ROUNDS];   // dest in buffer 0
  int           lstr[ROUNDS];   // element stride buffer0 -> buffer1
#pragma unroll
  for (int r = 0; r < ROUNDS; ++r) {
    const int id = r * 4 + w;
    if (id < ASUB) {
      const int ks = id >> 3, ms = id & 7;
      gptr[r] = A + (size_t)(m0 + ms*16 + srow) * K + ks*32 + (skq << 3);
      lptr[r] = &As[0][ks * 4096 + ms * 512];
      lstr[r] = 4096 * KS;
    } else {
      const int j = id - ASUB, ks = j / (NT/16), ns = j % (NT/16);
      gptr[r] = Bw + (size_t)(n0 + ns*16 + srow) * K + ks*32 + (skq << 3);
      lptr[r] = &Bs[0][ks * (NT*32) + ns * 512];
      lstr[r] = NT * 32 * KS;
    }
  }

  auto stage = [&](int kk, int b) {
#pragma unroll
    for (int r = 0; r < ROUNDS; ++r)
      gload16(gptr[r] + kk * BK, lptr[r] + b * lstr[r]);
  };
  auto compute = [&](int b) {
#pragma unroll
    for (int ks = 0; ks < KS; ++ks) {
      bf16x8 af[4], bfr[CT];
#pragma unroll
      for (int i = 0; i < 4; ++i)
        af[i] = *(const bf16x8*)&As[b][ks*4096 + (wm*4 + i)*512 + lane*8];
#pragma unroll
      for (int j = 0; j < CT; ++j)
        bfr[j] = *(const bf16x8*)&Bs[b][ks*(NT*32) + (wn*CT + j)*512 + lane*8];
#pragma unroll
      for (int i = 0; i < 4; ++i)
#pragma unroll
        for (int j = 0; j < CT; ++j)
          acc[i][j] = mfma16(af[i], bfr[j], acc[i][j]);
    }
  };

  const int NIT = K / BK;
  stage(0, 0);
  __syncthreads();
  for (int k = 0; k < NIT; ++k) {
    const int b = k & 1;
    if (k + 1 < NIT) stage(k + 1, b ^ 1);
    compute(b);
    __syncthreads();
  }

  const int quad = lane >> 4, cc = lane & 15;
#pragma unroll
  for (int rt = 0; rt < 4; ++rt) {
#pragma unroll
    for (int ct = 0; ct < CT; ++ct) {
      const int gr0 = m0 + (wm*4 + rt)*16 + quad*4;
      const int gc  = n0 + (wn*CT + ct)*16 + cc;
      f32x4 a = acc[rt][ct];
      if constexpr (EPI == 0) {
        const int bb = gr0 >> 10, nn = gr0 & 1023;  // gr0 % 4 == 0, no 1024-crossing in 4 rows
        if (gc >= 768) {
          // v: write transposed [B,H,64,N], packed 4 consecutive n
          const int jj = gc - 768, hh = jj >> 6, dh = jj & 63;
          bf16x4 pk = {(__bf16)a[0], (__bf16)a[1], (__bf16)a[2], (__bf16)a[3]};
          *(bf16x4*)&vt_out[((size_t)((bb*6 + hh)*64 + dh) << 10) + nn] = pk;
        } else {
          const bool isq = (gc < 384);
          const int jj = isq ? gc : (gc - 384);
          __bf16* dst = isq ? q_out : k_out;
          const float sc = isq ? 0.18033688011112042f : 1.0f; // (1/8)*log2(e) folded into q
          const int hh = jj >> 6, dh = jj & 63;
#pragma unroll
          for (int i = 0; i < 4; ++i)
            dst[((size_t)(((bb*6 + hh) << 10) | (nn + i)) << 6) + dh] = (__bf16)(a[i] * sc);
        }
      } else {
#pragma unroll
        for (int i = 0; i < 4; ++i) {
          const int gr = gr0 + i;
          float val = a[i];
          if constexpr (EPI == 1) {
            const size_t idx = (size_t)gr * N + gc;
            outf[idx] = val + bias[gc] + resid[idx];
          } else if constexpr (EPI == 2) {
            outb[(size_t)gr * N + gc] = (__bf16)fast_gelu(val + bias[gc]);
          } else {
            const size_t idx = (size_t)gr * N + gc;
            outf[idx] = outf[idx] + val + bias[gc];
          }
        }
      }
    }
  }
}

// ---------------------------------------------------------------- flash attention v3
// S^T = K*Q^T orientation, no max subtraction (scores ~|1|, scale*log2e folded into q),
// double-buffered K/V staging, one barrier per chunk. grid (96 bh, 8 qtiles):
// 96 % 8 == 0 -> all q-tiles of a bh on one XCD, K/V L2-resident.
__global__ __launch_bounds__(256, 3) void attn_kernel(
    const __bf16* __restrict__ qp, const __bf16* __restrict__ kp,
    const __bf16* __restrict__ vtp, __bf16* __restrict__ omat)
{
  __shared__ __attribute__((aligned(16))) __bf16 Ks[2][4096];     // 64 keys x 64 d, frag-ordered
  __shared__ __attribute__((aligned(16))) __bf16 Vs[2][4096];     // 64 d x 64 keys (from v^T)
  __shared__ __attribute__((aligned(16))) __bf16 Ps[4][2][1088];  // per-wave per-qtile 16 x 68
  const int tid = threadIdx.x, lane = tid & 63, w = tid >> 6;
  const int bh = blockIdx.x;
  const int q0 = blockIdx.y * 128 + w * 32;
  const int quad = lane >> 4, lo = lane & 15;

  // Q as B-operand fragments (lane&15 = q, quad*8+j = d), held in registers
  bf16x8 qa[2][2];
#pragma unroll
  for (int t = 0; t < 2; ++t) {
    const __bf16* qb = qp + ((size_t)bh * 1024 + q0 + t*16 + lo) * 64 + (quad << 3);
    qa[t][0] = *(const bf16x8*)qb;
    qa[t][1] = *(const bf16x8*)(qb + 32);
  }

  f32x4 oacc[2][4] = {};
  float l_r[2] = {0.f, 0.f};

  auto stage = [&](int c, int bb) {
#pragma unroll
    for (int s = 0; s < 2; ++s) {
      const int ck = s * 256 + tid;
      const int l = ck & 63, g = ck >> 6;       // g in [0,8)
      const int ct = g >> 1, ks = g & 1;
      const __bf16* gk = kp + ((size_t)bh*1024 + c*64 + ct*16 + (l & 15)) * 64
                            + ks*32 + ((l >> 4) << 3);
      gload16(gk, &Ks[bb][(ck & ~63) * 8]);
      const __bf16* gv = vtp + (((size_t)(bh*64 + ct*16 + (l & 15))) << 10)
                             + c*64 + ks*32 + ((l >> 4) << 3);
      gload16(gv, &Vs[bb][(ck & ~63) * 8]);
    }
  };

  stage(0, 0);
  __syncthreads();

  for (int c = 0; c < 16; ++c) {
    const int bb = c & 1;
    if (c + 1 < 16) stage(c + 1, bb ^ 1);

    // S^T tiles: D[m=key][n=q]; lane holds q=lo, keys quad*4+i
    f32x4 st[2][4];
#pragma unroll
    for (int ct = 0; ct < 4; ++ct) {
      bf16x8 kb0 = *(const bf16x8*)&Ks[bb][((ct*2 + 0)*64 + lane) * 8];
      bf16x8 kb1 = *(const bf16x8*)&Ks[bb][((ct*2 + 1)*64 + lane) * 8];
#pragma unroll
      for (int t = 0; t < 2; ++t) {
        f32x4 s0 = {};
        s0 = mfma16(kb0, qa[t][0], s0);
        s0 = mfma16(kb1, qa[t][1], s0);
        st[t][ct] = s0;
      }
    }
    // p = exp2(s); in-lane row-sum accumulation; packed b64 store
#pragma unroll
    for (int t = 0; t < 2; ++t)
#pragma unroll
      for (int ct = 0; ct < 4; ++ct) {
        const float p0 = __builtin_amdgcn_exp2f(st[t][ct][0]);
        const float p1 = __builtin_amdgcn_exp2f(st[t][ct][1]);
        const float p2 = __builtin_amdgcn_exp2f(st[t][ct][2]);
        const float p3 = __builtin_amdgcn_exp2f(st[t][ct][3]);
        l_r[t] += (p0 + p1) + (p2 + p3);
        bf16x4 pk = {(__bf16)p0, (__bf16)p1, (__bf16)p2, (__bf16)p3};
        *(bf16x4*)&Ps[w][t][lo*68 + ct*16 + quad*4] = pk;
      }
    // P as A-operand (lane&15 = q, quad*8+j = key)
    bf16x8 pa[2][2];
#pragma unroll
    for (int t = 0; t < 2; ++t)
#pragma unroll
      for (int ks = 0; ks < 2; ++ks)
        pa[t][ks] = *(const bf16x8*)&Ps[w][t][lo*68 + ks*32 + (quad << 3)];
    // O += P V
#pragma unroll
    for (int dt = 0; dt < 4; ++dt)
#pragma unroll
      for (int ks = 0; ks < 2; ++ks) {
        bf16x8 vb = *(const bf16x8*)&Vs[bb][((dt*2 + ks)*64 + lane) * 8];
#pragma unroll
        for (int t = 0; t < 2; ++t)
          oacc[t][dt] = mfma16(pa[t][ks], vb, oacc[t][dt]);
      }
    __syncthreads();
  }

  const int b = bh / 6, h = bh - (bh / 6) * 6;
#pragma unroll
  for (int t = 0; t < 2; ++t) {
    float ls = l_r[t];
    ls += __shfl_xor(ls, 16);
    ls += __shfl_xor(ls, 32);   // lane now holds sum for q = lane&15
#pragma unroll
    for (int i = 0; i < 4; ++i) {
      const float linv = 1.f / __shfl(ls, quad*4 + i);
      const int n = q0 + t*16 + quad*4 + i;
#pragma unroll
      for (int dt = 0; dt < 4; ++dt)
        omat[((size_t)((b << 10) | n)) * 384 + (h << 6) + dt*16 + lo] =
            (__bf16)(oacc[t][dt][i] * linv);
    }
  }
}

// ---------------------------------------------------------------- launch
extern "C" void kernel_launch(void* const* d_in, const int* in_sizes, int n_in,
                              void* d_out, int out_size, void* d_ws, size_t ws_size,
                              hipStream_t stream)
{
  const float* X    = (const float*)d_in[0];
  const float* Wq   = (const float*)d_in[1];
  const float* Wk   = (const float*)d_in[2];
  const float* Wv   = (const float*)d_in[3];
  const float* Wo   = (const float*)d_in[4];
  const float* bo   = (const float*)d_in[5];
  const float* ln1w = (const float*)d_in[6];
  const float* ln1b = (const float*)d_in[7];
  const float* ln2w = (const float*)d_in[8];
  const float* ln2b = (const float*)d_in[9];
  const float* W1   = (const float*)d_in[10];
  const float* b1   = (const float*)d_in[11];
  const float* W2   = (const float*)d_in[12];
  const float* b2   = (const float*)d_in[13];

  char* ws = (char*)d_ws;
  __bf16* t_bf  = (__bf16*)(ws + 0);           // [16384,384] bf16; reused as X2 bf16
  __bf16* q_bf  = (__bf16*)(ws + 12582912);    // [B,H,N,64] (pre-scaled by log2e/8)
  __bf16* k_bf  = (__bf16*)(ws + 25165824);    // [B,H,N,64]
  __bf16* omat  = (__bf16*)(ws + 37748736);    // [B,N,384] attention output
  __bf16* vt_bf = (__bf16*)(ws + 50331648);    // [B,H,64,N]
  float*  s1    = (float*) (ws + 62914560);    // [16384,384] f32; reused as h bf16
  __bf16* h_bf  = (__bf16*)(ws + 62914560);    // [16384,768] bf16
  __bf16* wqkv  = (__bf16*)(ws + 88080384);    // [1152,384]
  __bf16* wo_b  = (__bf16*)(ws + 88965120);    // [384,384]
  __bf16* w1_b  = (__bf16*)(ws + 89260032);    // [768,384]
  __bf16* w2_b  = (__bf16*)(ws + 89849856);    // [384,768]
  __bf16* x2_bf = t_bf;
  float*  out   = (float*)d_out;

  cvt_weights<<<1152, 256, 0, stream>>>(Wq, Wk, Wv, Wo, W1, W2, wqkv, wo_b, w1_b, w2_b);
  ln_kernel<0><<<4096, 256, 0, stream>>>(X, ln1w, ln1b, t_bf, nullptr);
  gemm_bt<0,128,32><<<dim3(128,9), 256, 0, stream>>>(t_bf, wqkv, 16384, 1152, 384,
      nullptr, nullptr, nullptr, nullptr, q_bf, k_bf, vt_bf);
  attn_kernel<<<dim3(96,8), 256, 0, stream>>>(q_bf, k_bf, vt_bf, omat);
  gemm_bt<1,64,64><<<dim3(128,6), 256, 0, stream>>>(omat, wo_b, 16384, 384, 384,
      bo, X, s1, nullptr, nullptr, nullptr, nullptr);
  ln_kernel<1><<<4096, 256, 0, stream>>>(s1, ln2w, ln2b, x2_bf, out);
  gemm_bt<2,128,64><<<dim3(128,6), 256, 0, stream>>>(x2_bf, w1_b, 16384, 768, 384,
      b1, nullptr, nullptr, h_bf, nullptr, nullptr, nullptr);
  gemm_bt<3,64,64><<<dim3(128,6), 256, 0, stream>>>(h_bf, w2_b, 16384, 384, 768,
      b2, nullptr, out, nullptr, nullptr, nullptr, nullptr);
}